// Round 4
// baseline (435.122 us; speedup 1.0000x reference)
//
#include <hip/hip_runtime.h>
#include <hip/hip_bf16.h>
#include <stdint.h>

// Problem constants (fixed by setup_inputs)
#define NTOK 8192
#define DMODEL 1280
#define NHEAD 16
#define HDIM 80
#define NSEG 16
#define SCALE_F 0.11180339887498949f
#define NEG_F -1e30f

typedef __bf16 bf16x8 __attribute__((ext_vector_type(8)));
typedef float f32x4 __attribute__((ext_vector_type(4)));

__device__ __forceinline__ void gload_lds16(const void* g, void* l) {
  __builtin_amdgcn_global_load_lds((__attribute__((address_space(1))) void*)g,
                                   (__attribute__((address_space(3))) void*)l,
                                   16, 0, 0);
}

// ---------------- fp32 -> bf16 convert (vectorized) ----------------
__global__ __launch_bounds__(256)
void cvt_f32_to_bf16(const float* __restrict__ src, __hip_bfloat16* __restrict__ dst) {
  int i = (blockIdx.x * 256 + threadIdx.x) * 4;
  float4 v = *(const float4*)(src + i);
  __align__(8) __hip_bfloat16 o[4] = {__float2bfloat16(v.x), __float2bfloat16(v.y),
                                      __float2bfloat16(v.z), __float2bfloat16(v.w)};
  *(uint2*)(dst + i) = *(const uint2*)o;
}

// ---------------- transpose fp32 (RxC) -> bf16 (CxR) ----------------
__global__ __launch_bounds__(256)
void transpose_w(const float* __restrict__ src, __hip_bfloat16* __restrict__ dst,
                 int R, int C) {
  __shared__ __hip_bfloat16 tile[32][33];
  int c0 = blockIdx.x * 32, r0 = blockIdx.y * 32;
  int tx = threadIdx.x & 31, ty = threadIdx.x >> 5;
#pragma unroll
  for (int i = 0; i < 4; ++i) {
    int r = ty + i * 8;
    tile[r][tx] = __float2bfloat16(src[(size_t)(r0 + r) * C + c0 + tx]);
  }
  __syncthreads();
#pragma unroll
  for (int i = 0; i < 4; ++i) {
    int r = ty + i * 8;
    dst[(size_t)(c0 + r) * R + r0 + tx] = tile[tx][r];
  }
}

// ---------------- RoPE in-place, vectorized: thread = (n, qk, h, pair-chunk) ----------------
__global__ __launch_bounds__(256)
void rope2(__hip_bfloat16* __restrict__ qkv,
           const float* __restrict__ cosb, const float* __restrict__ sinb) {
  int t = blockIdx.x * 256 + threadIdx.x;   // 8192*2*16*5 = 1,310,720 exactly
  int p = t % 5;
  int rest = t / 5;
  int h = rest & 15;
  int qk = (rest >> 4) & 1;
  int n = rest >> 5;
  size_t base = (size_t)n * 3840 + qk * 1280 + h * 80 + p * 8;
  const float* cb = cosb + n * 80 + p * 8;
  const float* sb = sinb + n * 80 + p * 8;
  float4 cA = *(const float4*)cb, cB = *(const float4*)(cb + 4);
  float4 cC = *(const float4*)(cb + 40), cD = *(const float4*)(cb + 44);
  float4 sA = *(const float4*)sb, sB = *(const float4*)(sb + 4);
  float4 sC = *(const float4*)(sb + 40), sD = *(const float4*)(sb + 44);
  float c0[8] = {cA.x, cA.y, cA.z, cA.w, cB.x, cB.y, cB.z, cB.w};
  float c1[8] = {cC.x, cC.y, cC.z, cC.w, cD.x, cD.y, cD.z, cD.w};
  float s0[8] = {sA.x, sA.y, sA.z, sA.w, sB.x, sB.y, sB.z, sB.w};
  float s1[8] = {sC.x, sC.y, sC.z, sC.w, sD.x, sD.y, sD.z, sD.w};
  uint4 lou = *(const uint4*)(qkv + base);
  uint4 hiu = *(const uint4*)(qkv + base + 40);
  __align__(16) __hip_bfloat16 lo[8], hh[8], olo[8], ohi[8];
  *(uint4*)lo = lou; *(uint4*)hh = hiu;
#pragma unroll
  for (int e = 0; e < 8; ++e) {
    float x0 = __bfloat162float(lo[e]);
    float x1 = __bfloat162float(hh[e]);
    olo[e] = __float2bfloat16(x0 * c0[e] - x1 * s0[e]);
    ohi[e] = __float2bfloat16(x1 * c1[e] + x0 * s1[e]);
  }
  *(uint4*)(qkv + base) = *(const uint4*)olo;
  *(uint4*)(qkv + base + 40) = *(const uint4*)ohi;
}

// ---------------- 128x128 bf16 MFMA GEMM: C = A(MxK,lda) * Bt(NxK)^T + bias ----------------
template <bool OUT_F32, bool A_F32>
__global__ __launch_bounds__(256)
void gemm128(const void* __restrict__ Av, int lda,
             const __hip_bfloat16* __restrict__ Bt,
             const float* __restrict__ bias,
             void* __restrict__ Cv, int M, int N, int K) {
  __shared__ __align__(16) __hip_bfloat16 lds[8192];  // A[128][32] @0, B[128][32] @4096
  const int tid = threadIdx.x;
  const int lane = tid & 63;
  const int wave = tid >> 6;
  const int wr = wave >> 1, wc = wave & 1;
  const int lr = lane & 15;
  const int lk = (lane >> 4) << 3;
  const int m0 = blockIdx.x * 128;
  const int n0 = blockIdx.y * 128;

  f32x4 zero = {0.f, 0.f, 0.f, 0.f};
  f32x4 acc[4][4];
#pragma unroll
  for (int i = 0; i < 4; ++i)
#pragma unroll
    for (int j = 0; j < 4; ++j) acc[i][j] = zero;

  for (int k0 = 0; k0 < K; k0 += 32) {
#pragma unroll
    for (int j = 0; j < 2; ++j) {
      int v = j * 256 + tid;
      int row = v >> 2;
      int cb = (v & 3) << 3;
      gload_lds16(Bt + (size_t)(n0 + row) * K + k0 + cb,
                  &lds[4096 + wave * 512 + j * 2048]);
    }
    if constexpr (A_F32) {
      const float* A32 = (const float*)Av;
      float4 vv[4];
#pragma unroll
      for (int j = 0; j < 4; ++j) {
        int task = j * 256 + tid;
        int row = task >> 3, cc = task & 7;
        vv[j] = *(const float4*)(A32 + (size_t)(m0 + row) * lda + k0 + cc * 4);
      }
#pragma unroll
      for (int j = 0; j < 4; ++j) {
        int task = j * 256 + tid;
        int row = task >> 3, cc = task & 7;
        __align__(8) __hip_bfloat16 t[4] = {
            __float2bfloat16(vv[j].x), __float2bfloat16(vv[j].y),
            __float2bfloat16(vv[j].z), __float2bfloat16(vv[j].w)};
        *(uint2*)&lds[row * 32 + cc * 4] = *(const uint2*)t;
      }
    } else {
      const __hip_bfloat16* Abf = (const __hip_bfloat16*)Av;
#pragma unroll
      for (int j = 0; j < 2; ++j) {
        int v = j * 256 + tid;
        int row = v >> 2;
        int cb = (v & 3) << 3;
        gload_lds16(Abf + (size_t)(m0 + row) * lda + k0 + cb,
                    &lds[wave * 512 + j * 2048]);
      }
    }
    __syncthreads();

    bf16x8 af[4], bfr[4];
#pragma unroll
    for (int i = 0; i < 4; ++i) {
      af[i]  = *(const bf16x8*)&lds[(wr * 64 + i * 16 + lr) * 32 + lk];
      bfr[i] = *(const bf16x8*)&lds[4096 + (wc * 64 + i * 16 + lr) * 32 + lk];
    }
#pragma unroll
    for (int i = 0; i < 4; ++i)
#pragma unroll
      for (int j = 0; j < 4; ++j)
        acc[i][j] = __builtin_amdgcn_mfma_f32_16x16x32_bf16(af[i], bfr[j], acc[i][j], 0, 0, 0);
    __syncthreads();
  }

  const int r0 = (lane >> 4) << 2;
#pragma unroll
  for (int j = 0; j < 4; ++j) {
    int col = n0 + wc * 64 + j * 16 + lr;
    float bv = bias[col];
#pragma unroll
    for (int i = 0; i < 4; ++i) {
      int rowb = m0 + wr * 64 + i * 16 + r0;
#pragma unroll
      for (int r = 0; r < 4; ++r) {
        float val = acc[i][j][r] + bv;
        if (OUT_F32)
          ((float*)Cv)[(size_t)(rowb + r) * N + col] = val;
        else
          ((__hip_bfloat16*)Cv)[(size_t)(rowb + r) * N + col] = __float2bfloat16(val);
      }
    }
  }
}

// ---------------- varlen flash attention, KVBLK=64, pipelined reg-staging ----------------
// block = (qtile of 64 rows, head, seg); 4 waves x 16 q-rows; Q in registers.
// O written back into the Q slice of qkv.
__global__ __launch_bounds__(256, 4)
void attn_fwd(__hip_bfloat16* __restrict__ qkv, const int* __restrict__ cu) {
  const int qt = blockIdx.x, h = blockIdx.y, m = blockIdx.z;
  const int start = cu[m];
  const int L = cu[m + 1] - start;
  if (qt * 64 >= L) return;

  __shared__ __align__(16) __hip_bfloat16 Ks[64 * 104];     // [kv64][96+pad], cols 80..95 zeroed
  __shared__ __align__(16) __hip_bfloat16 Vs[80 * 72];      // [dim][kv64+pad]
  __shared__ __align__(16) __hip_bfloat16 Ps[4][16 * 72];   // per-wave P [q16][kv64+pad]

  const int tid = threadIdx.x;
  const int lane = tid & 63;
  const int wave = tid >> 6;
  const int lr = lane & 15;
  const int hi = lane >> 4;
  const int lk = hi * 8;
  const int nt = (L + 63) >> 6;

  // ---- Q fragments in registers (this wave's 16 q-rows, k = 0..95 with 80..95 zero) ----
  const int qr = qt * 64 + wave * 16 + lr;
  const __hip_bfloat16* qp = qkv + (size_t)(start + qr) * 3840 + h * 80;
  bf16x8 aq[3];
  aq[0] = *(const bf16x8*)(qp + lk);
  aq[1] = *(const bf16x8*)(qp + 32 + lk);
  {
    bf16x8 z;
#pragma unroll
    for (int e = 0; e < 8; ++e) z[e] = (__bf16)0.0f;
    aq[2] = z;
    if (hi < 2) aq[2] = *(const bf16x8*)(qp + 64 + lk);
  }

  // zero K pad columns 80..95 once
  if (tid < 128) {
    uint4 z4 = {0u, 0u, 0u, 0u};
    *(uint4*)&Ks[(tid >> 1) * 104 + 80 + (tid & 1) * 8] = z4;
  }

  const __hip_bfloat16* kbase = qkv + (size_t)start * 3840 + 1280 + h * 80;
  const __hip_bfloat16* vbase = qkv + (size_t)start * 3840 + 2560 + h * 80;

  // staging registers: chunk-major tasks, chunk c = wave+4j, row = lane
  uint4 kr[3], vr[3];
  auto loadkv = [&](int tile) {
    int row = tile * 64 + lane;
    if (row > L - 1) row = L - 1;
    size_t roff = (size_t)row * 3840;
#pragma unroll
    for (int j = 0; j < 3; ++j) {
      int c = wave + 4 * j;
      if (c < 10) {
        kr[j] = *(const uint4*)(kbase + roff + c * 8);
        vr[j] = *(const uint4*)(vbase + roff + c * 8);
      }
    }
  };
  auto writekv = [&]() {
#pragma unroll
    for (int j = 0; j < 3; ++j) {
      int c = wave + 4 * j;
      if (c < 10) {
        *(uint4*)&Ks[lane * 104 + c * 8] = kr[j];
        __align__(16) __hip_bfloat16 tmp[8];
        *(uint4*)tmp = vr[j];
#pragma unroll
        for (int e = 0; e < 8; ++e) Vs[(c * 8 + e) * 72 + lane] = tmp[e];
      }
    }
  };

  loadkv(0);
  writekv();
  loadkv(nt > 1 ? 1 : 0);

  float m_run[4], l_run[4];
  f32x4 fz = {0.f, 0.f, 0.f, 0.f};
  f32x4 accO[5];
#pragma unroll
  for (int r = 0; r < 4; ++r) { m_run[r] = NEG_F; l_run[r] = 0.f; }
#pragma unroll
  for (int d = 0; d < 5; ++d) accO[d] = fz;

  __syncthreads();

  for (int t = 0; t < nt; ++t) {
    const int kt0 = t * 64;
    // ---- QK^T : S (16 q-rows x 64 kv) per wave ----
    f32x4 s[4] = {fz, fz, fz, fz};
#pragma unroll
    for (int ks = 0; ks < 3; ++ks) {
#pragma unroll
      for (int j = 0; j < 4; ++j) {
        bf16x8 bk = *(const bf16x8*)&Ks[(j * 16 + lr) * 104 + ks * 32 + lk];
        s[j] = __builtin_amdgcn_mfma_f32_16x16x32_bf16(aq[ks], bk, s[j], 0, 0, 0);
      }
    }
    // ---- mask + scale ----
#pragma unroll
    for (int j = 0; j < 4; ++j) {
      bool vj = (kt0 + j * 16 + lr) < L;
#pragma unroll
      for (int r = 0; r < 4; ++r)
        s[j][r] = vj ? s[j][r] * SCALE_F : NEG_F;
    }
    // ---- online softmax (row = hi*4+r across 16 lanes) ----
    float mx[4];
#pragma unroll
    for (int r = 0; r < 4; ++r)
      mx[r] = fmaxf(fmaxf(s[0][r], s[1][r]), fmaxf(s[2][r], s[3][r]));
#pragma unroll
    for (int off = 1; off < 16; off <<= 1)
#pragma unroll
      for (int r = 0; r < 4; ++r)
        mx[r] = fmaxf(mx[r], __shfl_xor(mx[r], off, 64));
    float rs[4];
#pragma unroll
    for (int r = 0; r < 4; ++r) {
      float mn = fmaxf(m_run[r], mx[r]);
      float sf = __expf(m_run[r] - mn);
      m_run[r] = mn;
      float a0 = __expf(s[0][r] - mn); s[0][r] = a0;
      float a1 = __expf(s[1][r] - mn); s[1][r] = a1;
      float a2 = __expf(s[2][r] - mn); s[2][r] = a2;
      float a3 = __expf(s[3][r] - mn); s[3][r] = a3;
      rs[r] = (a0 + a1) + (a2 + a3);
      l_run[r] *= sf;
#pragma unroll
      for (int d = 0; d < 5; ++d) accO[d][r] *= sf;
    }
#pragma unroll
    for (int off = 1; off < 16; off <<= 1)
#pragma unroll
      for (int r = 0; r < 4; ++r)
        rs[r] += __shfl_xor(rs[r], off, 64);
#pragma unroll
    for (int r = 0; r < 4; ++r) l_run[r] += rs[r];

    // ---- P -> per-wave LDS (bf16) ----
    __hip_bfloat16* pw = &Ps[wave][0];
#pragma unroll
    for (int j = 0; j < 4; ++j)
#pragma unroll
      for (int r = 0; r < 4; ++r)
        pw[(hi * 4 + r) * 72 + j * 16 + lr] = __float2bfloat16(s[j][r]);
    asm volatile("s_waitcnt lgkmcnt(0)" ::: "memory");
    __builtin_amdgcn_sched_barrier(0);
    // ---- PV ----
    bf16x8 ap0 = *(const bf16x8*)&pw[lr * 72 + lk];
    bf16x8 ap1 = *(const bf16x8*)&pw[lr * 72 + 32 + lk];
#pragma unroll
    for (int d = 0; d < 5; ++d) {
      bf16x8 bv0 = *(const bf16x8*)&Vs[(d * 16 + lr) * 72 + lk];
      bf16x8 bv1 = *(const bf16x8*)&Vs[(d * 16 + lr) * 72 + 32 + lk];
      accO[d] = __builtin_amdgcn_mfma_f32_16x16x32_bf16(ap0, bv0, accO[d], 0, 0, 0);
      accO[d] = __builtin_amdgcn_mfma_f32_16x16x32_bf16(ap1, bv1, accO[d], 0, 0, 0);
    }

    __syncthreads();
    if (t + 1 < nt) {
      writekv();                                  // tile t+1 (loaded 1 phase ago)
      loadkv(t + 2 < nt ? t + 2 : nt - 1);        // prefetch tile t+2
      __syncthreads();
    }
  }

  // ---- epilogue: O / l -> back into Q slice of qkv ----
#pragma unroll
  for (int d = 0; d < 5; ++d)
#pragma unroll
    for (int r = 0; r < 4; ++r) {
      int row = qt * 64 + wave * 16 + hi * 4 + r;
      qkv[(size_t)(start + row) * 3840 + h * 80 + d * 16 + lr] =
          __float2bfloat16(accO[d][r] / l_run[r]);
    }
}

extern "C" void kernel_launch(void* const* d_in, const int* in_sizes, int n_in,
                              void* d_out, int out_size, void* d_ws, size_t ws_size,
                              hipStream_t stream) {
  const float* hidden = (const float*)d_in[0];
  const int*   cu     = (const int*)d_in[1];
  const float* cosb   = (const float*)d_in[2];
  const float* sinb   = (const float*)d_in[3];
  const float* Wqkv   = (const float*)d_in[4];
  const float* bqkv   = (const float*)d_in[5];
  const float* Wproj  = (const float*)d_in[6];
  const float* bproj  = (const float*)d_in[7];
  float* out = (float*)d_out;
  char* ws = (char*)d_ws;

  // workspace layout (bytes), required floor = 76,021,760
  __hip_bfloat16* qkv    = (__hip_bfloat16*)(ws);              // 8192x3840 bf16 (62.9MB)
  __hip_bfloat16* wqkvT  = (__hip_bfloat16*)(ws + 62914560);   // 3840x1280 (9.8MB)
  __hip_bfloat16* wprojT = (__hip_bfloat16*)(ws + 72744960);   // 1280x1280 (3.3MB)
  __hip_bfloat16* hbf    = (__hip_bfloat16*)(ws + 76021760);   // optional 8192x1280 (21MB)
  const bool use_hbf = ws_size >= (size_t)96993280;

  transpose_w<<<dim3(120, 40), 256, 0, stream>>>(Wqkv, wqkvT, 1280, 3840);
  transpose_w<<<dim3(40, 40), 256, 0, stream>>>(Wproj, wprojT, 1280, 1280);
  if (use_hbf) {
    cvt_f32_to_bf16<<<10240, 256, 0, stream>>>(hidden, hbf);
    gemm128<false, false><<<dim3(64, 30), 256, 0, stream>>>(hbf, 1280, wqkvT, bqkv, qkv, 8192, 3840, 1280);
  } else {
    gemm128<false, true><<<dim3(64, 30), 256, 0, stream>>>(hidden, 1280, wqkvT, bqkv, qkv, 8192, 3840, 1280);
  }
  rope2<<<5120, 256, 0, stream>>>(qkv, cosb, sinb);
  attn_fwd<<<dim3(16, 16, 16), 256, 0, stream>>>(qkv, cu);
  gemm128<true, false><<<dim3(64, 10), 256, 0, stream>>>(qkv, 3840, wprojT, bproj, out, 8192, 1280, 1280);
}

// Round 5
// 320.973 us; speedup vs baseline: 1.3556x; 1.3556x over previous
//
#include <hip/hip_runtime.h>
#include <hip/hip_bf16.h>
#include <stdint.h>

// Problem constants (fixed by setup_inputs)
#define NTOK 8192
#define DMODEL 1280
#define NHEAD 16
#define HDIM 80
#define NSEG 16
#define SCALE_F 0.11180339887498949f
#define NEG_F -1e30f

typedef __bf16 bf16x8 __attribute__((ext_vector_type(8)));
typedef float f32x4 __attribute__((ext_vector_type(4)));

__device__ __forceinline__ void gload_lds16(const void* g, void* l) {
  __builtin_amdgcn_global_load_lds((__attribute__((address_space(1))) void*)g,
                                   (__attribute__((address_space(3))) void*)l,
                                   16, 0, 0);
}

// ---------------- fp32 -> bf16 convert (vectorized) ----------------
__global__ __launch_bounds__(256)
void cvt_f32_to_bf16(const float* __restrict__ src, __hip_bfloat16* __restrict__ dst) {
  int i = (blockIdx.x * 256 + threadIdx.x) * 4;
  float4 v = *(const float4*)(src + i);
  __align__(8) __hip_bfloat16 o[4] = {__float2bfloat16(v.x), __float2bfloat16(v.y),
                                      __float2bfloat16(v.z), __float2bfloat16(v.w)};
  *(uint2*)(dst + i) = *(const uint2*)o;
}

// ---------------- transpose fp32 (RxC) -> bf16 (CxR) ----------------
__global__ __launch_bounds__(256)
void transpose_w(const float* __restrict__ src, __hip_bfloat16* __restrict__ dst,
                 int R, int C) {
  __shared__ __hip_bfloat16 tile[32][33];
  int c0 = blockIdx.x * 32, r0 = blockIdx.y * 32;
  int tx = threadIdx.x & 31, ty = threadIdx.x >> 5;
#pragma unroll
  for (int i = 0; i < 4; ++i) {
    int r = ty + i * 8;
    tile[r][tx] = __float2bfloat16(src[(size_t)(r0 + r) * C + c0 + tx]);
  }
  __syncthreads();
#pragma unroll
  for (int i = 0; i < 4; ++i) {
    int r = ty + i * 8;
    dst[(size_t)(c0 + r) * R + r0 + tx] = tile[tx][r];
  }
}

// ---------------- RoPE in-place, vectorized: thread = (n, qk, h, pair-chunk) ----------------
__global__ __launch_bounds__(256)
void rope2(__hip_bfloat16* __restrict__ qkv,
           const float* __restrict__ cosb, const float* __restrict__ sinb) {
  int t = blockIdx.x * 256 + threadIdx.x;   // 8192*2*16*5 = 1,310,720 exactly
  int p = t % 5;
  int rest = t / 5;
  int h = rest & 15;
  int qk = (rest >> 4) & 1;
  int n = rest >> 5;
  size_t base = (size_t)n * 3840 + qk * 1280 + h * 80 + p * 8;
  const float* cb = cosb + n * 80 + p * 8;
  const float* sb = sinb + n * 80 + p * 8;
  float4 cA = *(const float4*)cb, cB = *(const float4*)(cb + 4);
  float4 cC = *(const float4*)(cb + 40), cD = *(const float4*)(cb + 44);
  float4 sA = *(const float4*)sb, sB = *(const float4*)(sb + 4);
  float4 sC = *(const float4*)(sb + 40), sD = *(const float4*)(sb + 44);
  float c0[8] = {cA.x, cA.y, cA.z, cA.w, cB.x, cB.y, cB.z, cB.w};
  float c1[8] = {cC.x, cC.y, cC.z, cC.w, cD.x, cD.y, cD.z, cD.w};
  float s0[8] = {sA.x, sA.y, sA.z, sA.w, sB.x, sB.y, sB.z, sB.w};
  float s1[8] = {sC.x, sC.y, sC.z, sC.w, sD.x, sD.y, sD.z, sD.w};
  uint4 lou = *(const uint4*)(qkv + base);
  uint4 hiu = *(const uint4*)(qkv + base + 40);
  __align__(16) __hip_bfloat16 lo[8], hh[8], olo[8], ohi[8];
  *(uint4*)lo = lou; *(uint4*)hh = hiu;
#pragma unroll
  for (int e = 0; e < 8; ++e) {
    float x0 = __bfloat162float(lo[e]);
    float x1 = __bfloat162float(hh[e]);
    olo[e] = __float2bfloat16(x0 * c0[e] - x1 * s0[e]);
    ohi[e] = __float2bfloat16(x1 * c1[e] + x0 * s1[e]);
  }
  *(uint4*)(qkv + base) = *(const uint4*)olo;
  *(uint4*)(qkv + base + 40) = *(const uint4*)ohi;
}

// ---------------- 128x128 bf16 MFMA GEMM: C = A(MxK,lda) * Bt(NxK)^T + bias ----------------
template <bool OUT_F32, bool A_F32>
__global__ __launch_bounds__(256)
void gemm128(const void* __restrict__ Av, int lda,
             const __hip_bfloat16* __restrict__ Bt,
             const float* __restrict__ bias,
             void* __restrict__ Cv, int M, int N, int K) {
  __shared__ __align__(16) __hip_bfloat16 lds[8192];  // A[128][32] @0, B[128][32] @4096
  const int tid = threadIdx.x;
  const int lane = tid & 63;
  const int wave = tid >> 6;
  const int wr = wave >> 1, wc = wave & 1;
  const int lr = lane & 15;
  const int lk = (lane >> 4) << 3;
  const int m0 = blockIdx.x * 128;
  const int n0 = blockIdx.y * 128;

  f32x4 zero = {0.f, 0.f, 0.f, 0.f};
  f32x4 acc[4][4];
#pragma unroll
  for (int i = 0; i < 4; ++i)
#pragma unroll
    for (int j = 0; j < 4; ++j) acc[i][j] = zero;

  for (int k0 = 0; k0 < K; k0 += 32) {
#pragma unroll
    for (int j = 0; j < 2; ++j) {
      int v = j * 256 + tid;
      int row = v >> 2;
      int cb = (v & 3) << 3;
      gload_lds16(Bt + (size_t)(n0 + row) * K + k0 + cb,
                  &lds[4096 + wave * 512 + j * 2048]);
    }
    if constexpr (A_F32) {
      const float* A32 = (const float*)Av;
      float4 vv[4];
#pragma unroll
      for (int j = 0; j < 4; ++j) {
        int task = j * 256 + tid;
        int row = task >> 3, cc = task & 7;
        vv[j] = *(const float4*)(A32 + (size_t)(m0 + row) * lda + k0 + cc * 4);
      }
#pragma unroll
      for (int j = 0; j < 4; ++j) {
        int task = j * 256 + tid;
        int row = task >> 3, cc = task & 7;
        __align__(8) __hip_bfloat16 t[4] = {
            __float2bfloat16(vv[j].x), __float2bfloat16(vv[j].y),
            __float2bfloat16(vv[j].z), __float2bfloat16(vv[j].w)};
        *(uint2*)&lds[row * 32 + cc * 4] = *(const uint2*)t;
      }
    } else {
      const __hip_bfloat16* Abf = (const __hip_bfloat16*)Av;
#pragma unroll
      for (int j = 0; j < 2; ++j) {
        int v = j * 256 + tid;
        int row = v >> 2;
        int cb = (v & 3) << 3;
        gload_lds16(Abf + (size_t)(m0 + row) * lda + k0 + cb,
                    &lds[wave * 512 + j * 2048]);
      }
    }
    __syncthreads();

    bf16x8 af[4], bfr[4];
#pragma unroll
    for (int i = 0; i < 4; ++i) {
      af[i]  = *(const bf16x8*)&lds[(wr * 64 + i * 16 + lr) * 32 + lk];
      bfr[i] = *(const bf16x8*)&lds[4096 + (wc * 64 + i * 16 + lr) * 32 + lk];
    }
#pragma unroll
    for (int i = 0; i < 4; ++i)
#pragma unroll
      for (int j = 0; j < 4; ++j)
        acc[i][j] = __builtin_amdgcn_mfma_f32_16x16x32_bf16(af[i], bfr[j], acc[i][j], 0, 0, 0);
    __syncthreads();
  }

  const int r0 = (lane >> 4) << 2;
#pragma unroll
  for (int j = 0; j < 4; ++j) {
    int col = n0 + wc * 64 + j * 16 + lr;
    float bv = bias[col];
#pragma unroll
    for (int i = 0; i < 4; ++i) {
      int rowb = m0 + wr * 64 + i * 16 + r0;
#pragma unroll
      for (int r = 0; r < 4; ++r) {
        float val = acc[i][j][r] + bv;
        if (OUT_F32)
          ((float*)Cv)[(size_t)(rowb + r) * N + col] = val;
        else
          ((__hip_bfloat16*)Cv)[(size_t)(rowb + r) * N + col] = __float2bfloat16(val);
      }
    }
  }
}

// ---------------- varlen flash attention v3 ----------------
// block = one (seg, qt-tile of 128 rows) x head; 4 waves x 32 q-rows.
// K: global_load_lds DMA into linear [64][80] (no regs, no pre-compute wait).
// V: T14 split (load regs at compute start, transpose-scatter after PV).
// Double-buffered K/V, 1 barrier per KV-tile. O written into Q slice of qkv.
__global__ __launch_bounds__(256, 2)
void attn_fwd(__hip_bfloat16* __restrict__ qkv, const int* __restrict__ cu) {
  const int h = blockIdx.y;
  const int pid = blockIdx.x;
  // decode (seg, qt) from pid via cu scan (uniform)
  int seg = -1, qt = 0, start = 0, L = 0;
  int accq = 0;
#pragma unroll 1
  for (int s2 = 0; s2 < NSEG; ++s2) {
    int st = cu[s2], en = cu[s2 + 1];
    int len = en - st;
    int nq = (len + 127) >> 7;
    if (seg < 0 && pid < accq + nq) { seg = s2; qt = pid - accq; start = st; L = len; }
    accq += nq;
  }
  if (seg < 0) return;

  __shared__ __align__(16) __hip_bfloat16 Ks[2][64 * 80];   // linear, DMA target
  __shared__ __align__(16) __hip_bfloat16 Vs[2][80 * 72];   // [dim][kv64+pad]
  __shared__ __align__(16) __hip_bfloat16 Ps[4][32 * 72];   // per-wave P [q32][kv64+pad]

  const int tid = threadIdx.x;
  const int lane = tid & 63;
  const int wave = tid >> 6;
  const int lr = lane & 15;
  const int hi = lane >> 4;
  const int lk = hi * 8;
  const int nt = (L + 63) >> 6;

  // ---- Q fragments in registers, pre-scaled by SCALE_F ----
  // aq[f][ks]: rows qt*128 + wave*32 + f*16 + lr, k = ks*32 + hi*8 + e (k>=80 zero)
  bf16x8 aq[2][3];
  {
    bf16x8 z;
#pragma unroll
    for (int e = 0; e < 8; ++e) z[e] = (__bf16)0.0f;
#pragma unroll
    for (int f = 0; f < 2; ++f) {
      int qr = qt * 128 + wave * 32 + f * 16 + lr;
      if (qr > L - 1) qr = L - 1;
      const __hip_bfloat16* qp = qkv + (size_t)(start + qr) * 3840 + h * 80;
      bf16x8 a0 = *(const bf16x8*)(qp + lk);
      bf16x8 a1 = *(const bf16x8*)(qp + 32 + lk);
      bf16x8 a2 = (hi < 2) ? *(const bf16x8*)(qp + 64 + lk) : z;
#pragma unroll
      for (int e = 0; e < 8; ++e) {
        a0[e] = (__bf16)((float)a0[e] * SCALE_F);
        a1[e] = (__bf16)((float)a1[e] * SCALE_F);
        a2[e] = (__bf16)((float)a2[e] * SCALE_F);
      }
      aq[f][0] = a0; aq[f][1] = a1; aq[f][2] = a2;
    }
  }

  const __hip_bfloat16* kbase = qkv + (size_t)start * 3840 + 1280 + h * 80;
  const __hip_bfloat16* vbase = qkv + (size_t)start * 3840 + 2560 + h * 80;

  // K DMA: 10 x 1KB instructions cover [64][80] bf16; wave w issues i = w+4j
  auto stageK = [&](int t, int buf) {
#pragma unroll
    for (int j = 0; j < 3; ++j) {
      int i = wave + 4 * j;
      if (i < 10) {
        int E = i * 512 + lane * 8;
        int r = E / 80;
        int c = E - r * 80;
        int g = t * 64 + r;
        if (g > L - 1) g = L - 1;
        gload_lds16(kbase + (size_t)g * 3840 + c, (char*)&Ks[buf][0] + i * 1024);
      }
    }
  };
  uint4 vr[3];
  auto loadV = [&](int t) {
#pragma unroll
    for (int j = 0; j < 3; ++j) {
      int tsk = tid + j * 256;
      if (tsk < 640) {
        int r = tsk / 10, c = tsk - r * 10;
        int g = t * 64 + r;
        if (g > L - 1) g = L - 1;
        vr[j] = *(const uint4*)(vbase + (size_t)g * 3840 + c * 8);
      }
    }
  };
  auto writeV = [&](int buf) {
#pragma unroll
    for (int j = 0; j < 3; ++j) {
      int tsk = tid + j * 256;
      if (tsk < 640) {
        int r = tsk / 10, c = tsk - r * 10;
        __align__(16) __hip_bfloat16 tmp[8];
        *(uint4*)tmp = vr[j];
#pragma unroll
        for (int e = 0; e < 8; ++e) Vs[buf][(c * 8 + e) * 72 + r] = tmp[e];
      }
    }
  };

  float m_run[2][4], l_run[2][4];
  f32x4 fz = {0.f, 0.f, 0.f, 0.f};
  f32x4 accO[2][5];
#pragma unroll
  for (int f = 0; f < 2; ++f) {
#pragma unroll
    for (int r = 0; r < 4; ++r) { m_run[f][r] = NEG_F; l_run[f][r] = 0.f; }
#pragma unroll
    for (int d = 0; d < 5; ++d) accO[f][d] = fz;
  }

  // prologue: stage tile 0 into buf 0
  stageK(0, 0);
  loadV(0);
  writeV(0);
  __syncthreads();

  int cur = 0;
  for (int t = 0; t < nt; ++t) {
    const bool more = (t + 1 < nt);
    if (more) { stageK(t + 1, cur ^ 1); loadV(t + 1); }

    // ---- QK^T : S (32 q-rows x 64 kv) per wave ----
    f32x4 s[2][4];
#pragma unroll
    for (int f = 0; f < 2; ++f)
#pragma unroll
      for (int j = 0; j < 4; ++j) s[f][j] = fz;
#pragma unroll
    for (int ks = 0; ks < 3; ++ks) {
#pragma unroll
      for (int j = 0; j < 4; ++j) {
        // B-frag: K row j*16+lr, k = ks*32 + hi*8 (+e). k>=80 reads garbage, A is zero there.
        bf16x8 bk = *(const bf16x8*)&Ks[cur][(j * 16 + lr) * 80 + ks * 32 + lk];
        s[0][j] = __builtin_amdgcn_mfma_f32_16x16x32_bf16(aq[0][ks], bk, s[0][j], 0, 0, 0);
        s[1][j] = __builtin_amdgcn_mfma_f32_16x16x32_bf16(aq[1][ks], bk, s[1][j], 0, 0, 0);
      }
    }
    // ---- mask (scale pre-folded into Q) ----
#pragma unroll
    for (int j = 0; j < 4; ++j) {
      bool vj = (t * 64 + j * 16 + lr) < L;
#pragma unroll
      for (int f = 0; f < 2; ++f)
#pragma unroll
        for (int r = 0; r < 4; ++r)
          s[f][j][r] = vj ? s[f][j][r] : NEG_F;
    }
    // ---- online softmax, per frag (row = f, hi*4+r; 16 lanes of lr hold 64 kv over j) ----
#pragma unroll
    for (int f = 0; f < 2; ++f) {
      float mx[4];
#pragma unroll
      for (int r = 0; r < 4; ++r)
        mx[r] = fmaxf(fmaxf(s[f][0][r], s[f][1][r]), fmaxf(s[f][2][r], s[f][3][r]));
#pragma unroll
      for (int off = 1; off < 16; off <<= 1)
#pragma unroll
        for (int r = 0; r < 4; ++r)
          mx[r] = fmaxf(mx[r], __shfl_xor(mx[r], off, 64));
      float rs[4];
#pragma unroll
      for (int r = 0; r < 4; ++r) {
        float mn = fmaxf(m_run[f][r], mx[r]);
        float sf = __expf(m_run[f][r] - mn);
        m_run[f][r] = mn;
        float a0 = __expf(s[f][0][r] - mn); s[f][0][r] = a0;
        float a1 = __expf(s[f][1][r] - mn); s[f][1][r] = a1;
        float a2 = __expf(s[f][2][r] - mn); s[f][2][r] = a2;
        float a3 = __expf(s[f][3][r] - mn); s[f][3][r] = a3;
        rs[r] = (a0 + a1) + (a2 + a3);
        l_run[f][r] *= sf;
#pragma unroll
        for (int d = 0; d < 5; ++d) accO[f][d][r] *= sf;
      }
#pragma unroll
      for (int off = 1; off < 16; off <<= 1)
#pragma unroll
        for (int r = 0; r < 4; ++r)
          rs[r] += __shfl_xor(rs[r], off, 64);
#pragma unroll
      for (int r = 0; r < 4; ++r) l_run[f][r] += rs[r];
    }

    // ---- P -> per-wave LDS (bf16) ----
    __hip_bfloat16* pw = &Ps[wave][0];
#pragma unroll
    for (int f = 0; f < 2; ++f)
#pragma unroll
      for (int j = 0; j < 4; ++j)
#pragma unroll
        for (int r = 0; r < 4; ++r)
          pw[(f * 16 + hi * 4 + r) * 72 + j * 16 + lr] = __float2bfloat16(s[f][j][r]);
    asm volatile("s_waitcnt lgkmcnt(0)" ::: "memory");
    __builtin_amdgcn_sched_barrier(0);
    // ---- PV ----
    bf16x8 ap[2][2];
#pragma unroll
    for (int f = 0; f < 2; ++f) {
      ap[f][0] = *(const bf16x8*)&pw[(f * 16 + lr) * 72 + lk];
      ap[f][1] = *(const bf16x8*)&pw[(f * 16 + lr) * 72 + 32 + lk];
    }
#pragma unroll
    for (int d = 0; d < 5; ++d) {
      bf16x8 bv0 = *(const bf16x8*)&Vs[cur][(d * 16 + lr) * 72 + lk];
      bf16x8 bv1 = *(const bf16x8*)&Vs[cur][(d * 16 + lr) * 72 + 32 + lk];
      accO[0][d] = __builtin_amdgcn_mfma_f32_16x16x32_bf16(ap[0][0], bv0, accO[0][d], 0, 0, 0);
      accO[0][d] = __builtin_amdgcn_mfma_f32_16x16x32_bf16(ap[0][1], bv1, accO[0][d], 0, 0, 0);
      accO[1][d] = __builtin_amdgcn_mfma_f32_16x16x32_bf16(ap[1][0], bv0, accO[1][d], 0, 0, 0);
      accO[1][d] = __builtin_amdgcn_mfma_f32_16x16x32_bf16(ap[1][1], bv1, accO[1][d], 0, 0, 0);
    }

    if (more) writeV(cur ^ 1);   // vr arrived during compute (vmcnt wait here)
    __syncthreads();             // compiler drains vmcnt (K DMA) + lgkm before barrier
    if (more) cur ^= 1;
  }

  // ---- epilogue: O / l -> back into Q slice of qkv ----
#pragma unroll
  for (int f = 0; f < 2; ++f) {
    float rl[4];
#pragma unroll
    for (int r = 0; r < 4; ++r) rl[r] = 1.0f / l_run[f][r];
#pragma unroll
    for (int d = 0; d < 5; ++d)
#pragma unroll
      for (int r = 0; r < 4; ++r) {
        int row = qt * 128 + wave * 32 + f * 16 + hi * 4 + r;
        if (row < L)
          qkv[(size_t)(start + row) * 3840 + h * 80 + d * 16 + lr] =
              __float2bfloat16(accO[f][d][r] * rl[r]);
      }
  }
}

extern "C" void kernel_launch(void* const* d_in, const int* in_sizes, int n_in,
                              void* d_out, int out_size, void* d_ws, size_t ws_size,
                              hipStream_t stream) {
  const float* hidden = (const float*)d_in[0];
  const int*   cu     = (const int*)d_in[1];
  const float* cosb   = (const float*)d_in[2];
  const float* sinb   = (const float*)d_in[3];
  const float* Wqkv   = (const float*)d_in[4];
  const float* bqkv   = (const float*)d_in[5];
  const float* Wproj  = (const float*)d_in[6];
  const float* bproj  = (const float*)d_in[7];
  float* out = (float*)d_out;
  char* ws = (char*)d_ws;

  // workspace layout (bytes), required floor = 76,021,760
  __hip_bfloat16* qkv    = (__hip_bfloat16*)(ws);              // 8192x3840 bf16 (62.9MB)
  __hip_bfloat16* wqkvT  = (__hip_bfloat16*)(ws + 62914560);   // 3840x1280 (9.8MB)
  __hip_bfloat16* wprojT = (__hip_bfloat16*)(ws + 72744960);   // 1280x1280 (3.3MB)
  __hip_bfloat16* hbf    = (__hip_bfloat16*)(ws + 76021760);   // optional 8192x1280 (21MB)
  const bool use_hbf = ws_size >= (size_t)96993280;

  transpose_w<<<dim3(120, 40), 256, 0, stream>>>(Wqkv, wqkvT, 1280, 3840);
  transpose_w<<<dim3(40, 40), 256, 0, stream>>>(Wproj, wprojT, 1280, 1280);
  if (use_hbf) {
    cvt_f32_to_bf16<<<10240, 256, 0, stream>>>(hidden, hbf);
    gemm128<false, false><<<dim3(64, 30), 256, 0, stream>>>(hbf, 1280, wqkvT, bqkv, qkv, 8192, 3840, 1280);
  } else {
    gemm128<false, true><<<dim3(64, 30), 256, 0, stream>>>(hidden, 1280, wqkvT, bqkv, qkv, 8192, 3840, 1280);
  }
  rope2<<<5120, 256, 0, stream>>>(qkv, cosb, sinb);
  // grid.x = upper bound on sum of ceil(L/128) over segs: 8192/128 + 16 = 80
  attn_fwd<<<dim3(80, 16), 256, 0, stream>>>(qkv, cu);
  gemm128<true, false><<<dim3(64, 10), 256, 0, stream>>>(qkv, 3840, wprojT, bproj, out, 8192, 1280, 1280);
}